// Round 18
// baseline (14569.408 us; speedup 1.0000x reference)
//
#include <hip/hip_runtime.h>
#include <math.h>
#include <stdint.h>

#define LOG2PI 1.8378770664093453f

typedef __attribute__((ext_vector_type(8))) short bf8;   // 8 bf16
typedef __attribute__((ext_vector_type(4))) float f4;

__device__ __constant__ float ADc[6][5] = {
    {0.f,0.f,0.f,0.f,0.f},
    {0.2f,0.f,0.f,0.f,0.f},
    {0.075f,0.225f,0.f,0.f,0.f},
    {0.9777777778f,-3.7333333333f,3.5555555556f,0.f,0.f},
    {2.9525986893f,-11.5957933340f,9.8228928855f,-0.2908093278f,0.f},
    {2.8462752526f,-10.7575757576f,8.9064227177f,0.2784090909f,-0.2735313036f}};
__device__ __constant__ float CDc[6] = {0.f,0.2f,0.3f,0.8f,0.8888888889f,1.f};
__device__ __constant__ float Bcc[6] = {0.0911458333f,0.f,0.4492362983f,
    0.6510416667f,-0.3223761792f,0.1309523810f};

__device__ __forceinline__ short f2bf(float f) {
    uint32_t u = __float_as_uint(f);
    u += 0x7fffu + ((u >> 16) & 1u);          // RNE
    return (short)(u >> 16);
}
__device__ __forceinline__ float bf2f(unsigned short u) {
    return __uint_as_float(((uint32_t)u) << 16);
}
__device__ __forceinline__ float tanh_fast(float x) {
    float t = __builtin_amdgcn_exp2f(x * 2.88539008177793f);
    return 1.f - 2.f * __builtin_amdgcn_rcpf(1.f + t);
}
__device__ __forceinline__ bf8 ntl8(const short* p) {
    return *(const bf8*)p;
}
__device__ __forceinline__ void gload16(const void* g, void* l) {
    __builtin_amdgcn_global_load_lds(
        (const __attribute__((address_space(1))) uint32_t*)(uintptr_t)g,
        (__attribute__((address_space(3))) uint32_t*)(uintptr_t)l, 16, 0, 0);
}

struct FA {                      // per-flow pointer bundle
    short* Pcurb; const short* th1b; const short* vbufp;
    short* Pk; float* xf;
    const short* w2t; const short* w3c;
    const float* b2; const float* b3p; const float* b31; const float* wtp;
    float* L;
};

// ---------------------------------------------------------------------------
// Pair-stage kernel (R18): runs stages iA and iA+1 (pairs (0,1),(2,3),(4,5))
// of step s. Blocks 0-255 flow0 (32 rows each), 256-511 flow1. Body per stage
// = R16's proven stage2_k. Two pair-level optimizations:
//  - second stage reads its most-recent P (P_iA) from LDS rows 32-63 (still
//    staged there by the first stage's D-B) instead of global: -34MB/step x3.
//  - Pcur is bf16-only (f32 master dropped): stage-5 flat pass RMWs Pcurb.
// Per-stage dispatch keeps blocks phase-synchronized (R17 showed persistent
// blocks drift and lose the shared L2 weight stream: FETCH 8GB -> 13GB).
// ---------------------------------------------------------------------------
__global__ __launch_bounds__(512, 2) void pair2_k(
    FA f0, FA f1, int s, int iA,
    float db0, float db2, float db3, float db4, float db5)
{
    __shared__ char lds[65536];   // [64 rows][512 bf16]; a2 overlays rows 0-31
    const int tid = threadIdx.x, wave = tid >> 6, lane = tid & 63;
    const int lr = lane >> 4, lc = lane & 15;
    const int fl = blockIdx.x >> 8;
    const int bi = blockIdx.x & 255;
    const int m0 = bi * 32;
    const FA F = fl ? f1 : f0;
    const int dpad = fl ? 64 : 512;
    const size_t BH = (size_t)8192 * 512;

    #pragma unroll 1
    for (int i = iA; i < iA + 2; ++i) {
        const float ti = 1.f - 0.1f * (float)s - 0.1f * CDc[i];
        const float tcoef = -0.1f * Bcc[i];     // 0 for i==1
        const bool doTan = (i != 1);
        const bool pLds = (i == iA + 1);        // P_iA still staged in LDS
        float cj[5];
        #pragma unroll
        for (int j = 0; j < 5; ++j) cj[j] = -0.1f * ADc[i][j];

        // ---------------- Phase B (coalesced, bf8 granularity) ------------
        #pragma unroll
        for (int g = 0; g < 4; ++g) {
            int flat = (g << 12) + (tid << 3);    // 0..16383, 8-elem chunks
            int row = flat >> 9;                   // 0..31
            int cc  = flat & 511;                  // col, multiple of 8
            size_t gb = (((size_t)(m0 + row)) << 9) + cc;
            int wb = (row << 10) + ((cc << 1) ^ ((row & 7) << 4));
            bf8 pcb = ntl8(F.Pcurb + gb);
            float4 w0 = *(const float4*)(F.wtp + cc);
            float4 w1 = *(const float4*)(F.wtp + cc + 4);
            float wv[8] = {w0.x,w0.y,w0.z,w0.w,w1.x,w1.y,w1.z,w1.w};
            float pre[8];
            #pragma unroll
            for (int e = 0; e < 8; ++e)
                pre[e] = fmaf(ti, wv[e], bf2f((unsigned short)pcb[e]));
            #pragma unroll
            for (int j = 0; j < 5; ++j) {
                if (j < i) {
                    bf8 v = (pLds && j == iA)
                        ? *(const bf8*)(lds + 32768 + wb)     // staged P_iA
                        : ntl8(F.Pk + (size_t)j * BH + gb);
                    #pragma unroll
                    for (int e = 0; e < 8; ++e)
                        pre[e] = fmaf(cj[j], bf2f((unsigned short)v[e]), pre[e]);
                }
            }
            bf8 o1, o2;
            if (doTan) {
                bf8 th = ntl8(F.th1b + gb);
                #pragma unroll
                for (int e = 0; e < 8; ++e) {
                    float a = tanh_fast(pre[e]);
                    o1[e] = f2bf(a);
                    o2[e] = f2bf((1.f - a * a) * bf2f((unsigned short)th[e]));
                }
                *(bf8*)(lds + wb) = o1;
                *(bf8*)(lds + 32768 + wb) = o2;   // overwrites staged P chunk (already consumed above)
            } else {
                #pragma unroll
                for (int e = 0; e < 8; ++e) o1[e] = f2bf(tanh_fast(pre[e]));
                *(bf8*)(lds + wb) = o1;
            }
        }
        __syncthreads();

        // ---------------- Phase C: [a1;ta1](64) @ W2 ----------------------
        f4 acc[4][4];
        #pragma unroll
        for (int mt = 0; mt < 4; ++mt)
            #pragma unroll
            for (int nt = 0; nt < 4; ++nt) acc[mt][nt] = (f4)0.0f;
        {
            const short* wb = F.w2t + ((size_t)((wave << 6) + lc) << 9) + (lr << 3);
            bf8 bc[4], bn[4];
            #pragma unroll
            for (int nt = 0; nt < 4; ++nt) bc[nt] = *(const bf8*)(wb + (nt << 13));
            for (int kt = 0; kt < 16; ++kt) {
                bf8 af[4];
                int kb = (kt << 6) + (lr << 4);
                #pragma unroll
                for (int mt = 0; mt < 4; ++mt) {
                    if (mt >= 2 && !doTan) continue;
                    int lrow = (mt << 4) + lc;
                    af[mt] = *(const bf8*)(lds + (lrow << 10) + (kb ^ ((lrow & 7) << 4)));
                }
                if (kt < 15) {
                    #pragma unroll
                    for (int nt = 0; nt < 4; ++nt)
                        bn[nt] = *(const bf8*)(wb + (nt << 13) + ((kt + 1) << 5));
                }
                #pragma unroll
                for (int mt = 0; mt < 4; ++mt) {
                    if (mt >= 2 && !doTan) continue;
                    #pragma unroll
                    for (int nt = 0; nt < 4; ++nt)
                        acc[mt][nt] = __builtin_amdgcn_mfma_f32_16x16x32_bf16(
                            af[mt], bc[nt], acc[mt][nt], 0, 0, 0);
                }
                #pragma unroll
                for (int nt = 0; nt < 4; ++nt) bc[nt] = bn[nt];
            }
        }
        __syncthreads();   // all a1/ta1 reads done before a2 overlay

        // ---------------- Phase C epilogue: a2 -> rows 0-31; trace -> L ---
        {
            bf8 vb[4];
            if (doTan) {
                size_t vbase = ((size_t)((bi << 9) + tid)) << 5;
                #pragma unroll
                for (int q = 0; q < 4; ++q) vb[q] = ntl8(F.vbufp + vbase + (q << 3));
            }
            float trp[2][4] = {{0.f,0.f,0.f,0.f},{0.f,0.f,0.f,0.f}};
            #pragma unroll
            for (int mt = 0; mt < 2; ++mt)
                #pragma unroll
                for (int nt = 0; nt < 4; ++nt) {
                    int col = (wave << 6) + (nt << 4) + lc;
                    float bb = F.b2[col];
                    #pragma unroll
                    for (int r = 0; r < 4; ++r) {
                        int lrow = (mt << 4) + (lr << 2) + r;
                        float a = tanh_fast(acc[mt][nt][r] + bb);
                        *(short*)(lds + (lrow << 10) + ((col << 1) ^ ((lrow & 7) << 4))) = f2bf(a);
                        if (doTan) {
                            int e = nt * 8 + mt * 4 + r;
                            float ta2 = (1.f - a * a) * acc[mt + 2][nt][r];
                            trp[mt][r] = fmaf(ta2,
                                bf2f((unsigned short)vb[e >> 3][e & 7]), trp[mt][r]);
                        }
                    }
                }
            if (doTan) {
                #pragma unroll
                for (int mt = 0; mt < 2; ++mt)
                    #pragma unroll
                    for (int r = 0; r < 4; ++r) {
                        float v = trp[mt][r];
                        v += __shfl_xor(v, 1); v += __shfl_xor(v, 2);
                        v += __shfl_xor(v, 4); v += __shfl_xor(v, 8);
                        if (lc == 0)
                            atomicAdd(&F.L[m0 + (mt << 4) + (lr << 2) + r], tcoef * v);
                    }
            }
        }
        __syncthreads();   // a2 visible

        // ---------------- Phase D chunk A: xf += tcoef*(a2 @ W3 + b3) -----
        if (doTan) {
            if (fl == 0) {
                f4 aA[2][4];
                #pragma unroll
                for (int mt = 0; mt < 2; ++mt)
                    #pragma unroll
                    for (int nt = 0; nt < 4; ++nt) aA[mt][nt] = (f4)0.0f;
                const short* wA = F.w3c + ((size_t)((wave << 6) + lc) << 9) + (lr << 3);
                bf8 bc[4], bn[4];
                #pragma unroll
                for (int nt = 0; nt < 4; ++nt) bc[nt] = *(const bf8*)(wA + (nt << 13));
                for (int kt = 0; kt < 16; ++kt) {
                    bf8 af[2];
                    int kb = (kt << 6) + (lr << 4);
                    #pragma unroll
                    for (int mt = 0; mt < 2; ++mt) {
                        int lrow = (mt << 4) + lc;
                        af[mt] = *(const bf8*)(lds + (lrow << 10) + (kb ^ ((lrow & 7) << 4)));
                    }
                    if (kt < 15) {
                        #pragma unroll
                        for (int nt = 0; nt < 4; ++nt)
                            bn[nt] = *(const bf8*)(wA + (nt << 13) + ((kt + 1) << 5));
                    }
                    #pragma unroll
                    for (int mt = 0; mt < 2; ++mt)
                        #pragma unroll
                        for (int nt = 0; nt < 4; ++nt)
                            aA[mt][nt] = __builtin_amdgcn_mfma_f32_16x16x32_bf16(
                                af[mt], bc[nt], aA[mt][nt], 0, 0, 0);
                    #pragma unroll
                    for (int nt = 0; nt < 4; ++nt) bc[nt] = bn[nt];
                }
                #pragma unroll
                for (int mt = 0; mt < 2; ++mt)
                    #pragma unroll
                    for (int nt = 0; nt < 4; ++nt) {
                        int col = (wave << 6) + (nt << 4) + lc;
                        float bb = F.b3p[col];
                        #pragma unroll
                        for (int r = 0; r < 4; ++r) {
                            size_t grow = (size_t)(m0 + (mt << 4) + (lr << 2) + r);
                            size_t xi = (grow << 9) + col;
                            F.xf[xi] = fmaf(tcoef, aA[mt][nt][r] + bb, F.xf[xi]);
                        }
                    }
            } else if (wave < 4) {
                f4 aA[2];
                aA[0] = (f4)0.0f; aA[1] = (f4)0.0f;
                int col = (wave << 4) + lc;
                const short* wA = F.w3c + ((size_t)col << 9) + (lr << 3);
                bf8 bc = *(const bf8*)wA, bn;
                for (int kt = 0; kt < 16; ++kt) {
                    bf8 af[2];
                    int kb = (kt << 6) + (lr << 4);
                    #pragma unroll
                    for (int mt = 0; mt < 2; ++mt) {
                        int lrow = (mt << 4) + lc;
                        af[mt] = *(const bf8*)(lds + (lrow << 10) + (kb ^ ((lrow & 7) << 4)));
                    }
                    if (kt < 15) bn = *(const bf8*)(wA + ((kt + 1) << 5));
                    #pragma unroll
                    for (int mt = 0; mt < 2; ++mt)
                        aA[mt] = __builtin_amdgcn_mfma_f32_16x16x32_bf16(
                            af[mt], bc, aA[mt], 0, 0, 0);
                    bc = bn;
                }
                float bb = F.b3p[col];
                #pragma unroll
                for (int mt = 0; mt < 2; ++mt)
                    #pragma unroll
                    for (int r = 0; r < 4; ++r) {
                        size_t grow = (size_t)(m0 + (mt << 4) + (lr << 2) + r);
                        size_t xi = (grow << 6) + col;
                        F.xf[xi] = fmaf(tcoef, aA[mt][r] + bb, F.xf[xi]);
                    }
            }
        }

        // ---------------- Phase D chunk B: P = a2 @ W31 + b31 -------------
        {
            f4 aB[2][4];
            #pragma unroll
            for (int mt = 0; mt < 2; ++mt)
                #pragma unroll
                for (int nt = 0; nt < 4; ++nt) aB[mt][nt] = (f4)0.0f;
            const short* wB = F.w3c + ((size_t)(dpad + (wave << 6) + lc) << 9) + (lr << 3);
            bf8 bc[4], bn[4];
            #pragma unroll
            for (int nt = 0; nt < 4; ++nt) bc[nt] = *(const bf8*)(wB + (nt << 13));
            for (int kt = 0; kt < 16; ++kt) {
                bf8 af[2];
                int kb = (kt << 6) + (lr << 4);
                #pragma unroll
                for (int mt = 0; mt < 2; ++mt) {
                    int lrow = (mt << 4) + lc;
                    af[mt] = *(const bf8*)(lds + (lrow << 10) + (kb ^ ((lrow & 7) << 4)));
                }
                if (kt < 15) {
                    #pragma unroll
                    for (int nt = 0; nt < 4; ++nt)
                        bn[nt] = *(const bf8*)(wB + (nt << 13) + ((kt + 1) << 5));
                }
                #pragma unroll
                for (int mt = 0; mt < 2; ++mt)
                    #pragma unroll
                    for (int nt = 0; nt < 4; ++nt)
                        aB[mt][nt] = __builtin_amdgcn_mfma_f32_16x16x32_bf16(
                            af[mt], bc[nt], aB[mt][nt], 0, 0, 0);
                #pragma unroll
                for (int nt = 0; nt < 4; ++nt) bc[nt] = bn[nt];
            }
            __syncthreads();   // a2 reads done before P overlays rows 32-63
            // stage P fragments to LDS rows 32-63 (ta1 region, dead after C)
            #pragma unroll
            for (int mt = 0; mt < 2; ++mt)
                #pragma unroll
                for (int nt = 0; nt < 4; ++nt) {
                    int colh = (wave << 6) + (nt << 4) + lc;
                    float bb = F.b31[colh];
                    #pragma unroll
                    for (int r = 0; r < 4; ++r) {
                        int lrow = (mt << 4) + (lr << 2) + r;   // 0..31
                        *(short*)(lds + 32768 + (lrow << 10) +
                            ((colh << 1) ^ ((lrow & 7) << 4))) = f2bf(aB[mt][nt][r] + bb);
                    }
                }
        }
        __syncthreads();   // staged P visible

        // ---------------- flat coalesced P write / Pcur update ------------
        #pragma unroll
        for (int g = 0; g < 4; ++g) {
            int flat = (g << 12) + (tid << 3);
            int row = flat >> 9;
            int cc  = flat & 511;
            size_t gb = (((size_t)(m0 + row)) << 9) + cc;
            bf8 pv = *(const bf8*)(lds + 32768 + (row << 10) +
                                   ((cc << 1) ^ ((row & 7) << 4)));
            if (i < 5) {
                *(bf8*)(F.Pk + (size_t)i * BH + gb) = pv;
            } else {
                bf8 v0 = ntl8(F.Pk + 0 * BH + gb);
                bf8 v2 = ntl8(F.Pk + 2 * BH + gb);
                bf8 v3 = ntl8(F.Pk + 3 * BH + gb);
                bf8 v4 = ntl8(F.Pk + 4 * BH + gb);
                bf8 pc = ntl8(F.Pcurb + gb);
                bf8 ob;
                #pragma unroll
                for (int e = 0; e < 8; ++e) {
                    float pn = bf2f((unsigned short)pc[e]);
                    pn = fmaf(db0, bf2f((unsigned short)v0[e]), pn);
                    pn = fmaf(db2, bf2f((unsigned short)v2[e]), pn);
                    pn = fmaf(db3, bf2f((unsigned short)v3[e]), pn);
                    pn = fmaf(db4, bf2f((unsigned short)v4[e]), pn);
                    pn = fmaf(db5, bf2f((unsigned short)pv[e]), pn);
                    ob[e] = f2bf(pn);
                }
                *(bf8*)(F.Pcurb + gb) = ob;
            }
        }
        __syncthreads();   // flat-pass LDS reads done before next B writes
    }
}

// ---------------------------------------------------------------------------
// bf16 MFMA GEMM (precomputes): out(M x 512) = A(M x K) @ Bt(512 x K)^T + bias
// OUT 0: f32; OUT 1: bf16. grid (4, M/128).
// ---------------------------------------------------------------------------
template<int OUT>
__global__ __launch_bounds__(256) void mgemm0(
    const short* __restrict__ A, const short* __restrict__ Bt, int K,
    float* __restrict__ Cf, short* __restrict__ Cb,
    const float* __restrict__ bias)
{
    __shared__ char lds[32768];
    const int tid = threadIdx.x, wave = tid >> 6, lane = tid & 63;
    const int m0 = blockIdx.y * 128, n0 = blockIdx.x * 128;
    const int wr = wave >> 1, wc = wave & 1;

    f4 acc[4][4];
    #pragma unroll
    for (int m = 0; m < 4; ++m)
        #pragma unroll
        for (int n = 0; n < 4; ++n) acc[m][n] = (f4)0.0f;

    const int cbs  = (((lane & 7) ^ (lane >> 3)) << 4);
    const int lrow = lane >> 3;

    for (int k0 = 0; k0 < K; k0 += 64) {
        __syncthreads();
        #pragma unroll
        for (int i = 0; i < 4; ++i) {
            int q = wave * 4 + i;
            int row = q * 8 + lrow;
            gload16((const char*)(A  + (size_t)(m0 + row) * K + k0) + cbs, lds + q * 1024);
            gload16((const char*)(Bt + (size_t)(n0 + row) * K + k0) + cbs, lds + 16384 + q * 1024);
        }
        __syncthreads();
        #pragma unroll
        for (int kk = 0; kk < 2; ++kk) {
            bf8 af[4], bfr[4];
            #pragma unroll
            for (int m = 0; m < 4; ++m) {
                int row = wr * 64 + m * 16 + (lane & 15);
                int cb  = (((lane >> 4) << 4) + (kk << 6)) ^ ((row & 7) << 4);
                af[m] = *(const bf8*)(lds + row * 128 + cb);
            }
            #pragma unroll
            for (int n = 0; n < 4; ++n) {
                int row = wc * 64 + n * 16 + (lane & 15);
                int cb  = (((lane >> 4) << 4) + (kk << 6)) ^ ((row & 7) << 4);
                bfr[n] = *(const bf8*)(lds + 16384 + row * 128 + cb);
            }
            #pragma unroll
            for (int m = 0; m < 4; ++m)
                #pragma unroll
                for (int n = 0; n < 4; ++n)
                    acc[m][n] = __builtin_amdgcn_mfma_f32_16x16x32_bf16(
                        af[m], bfr[n], acc[m][n], 0, 0, 0);
        }
    }

    #pragma unroll
    for (int m = 0; m < 4; ++m)
        #pragma unroll
        for (int r = 0; r < 4; ++r) {
            int grow = m0 + wr * 64 + m * 16 + (lane >> 4) * 4 + r;
            #pragma unroll
            for (int n = 0; n < 4; ++n) {
                int gcol = n0 + wc * 64 + n * 16 + (lane & 15);
                float v = acc[m][n][r];
                if (bias) v += bias[gcol];
                if constexpr (OUT == 0) Cf[(size_t)grow * 512 + gcol] = v;
                else Cb[(size_t)grow * 512 + gcol] = f2bf(v);
            }
        }
}

// ---------------------------------------------------------------------------
// prep kernels
// ---------------------------------------------------------------------------
__global__ __launch_bounds__(256) void buildw1x(
    short* __restrict__ out, const float* __restrict__ W1,
    int D, int Dpad, int Kext, int extN, int rowE, int rowC, int total)
{
    int i = blockIdx.x * 256 + threadIdx.x;
    if (i >= total) return;
    int n = i / Kext, k = i - n * Kext;
    float v = 0.f;
    if (k < D) v = W1[(size_t)k * 512 + n];
    else if (k >= Dpad) {
        int j = k - Dpad;
        if (j < extN)       v = W1[(size_t)(rowE + j) * 512 + n];
        else if (j == extN) v = W1[(size_t)rowC * 512 + n];
    }
    out[i] = f2bf(v);
}

__global__ __launch_bounds__(256) void buildab(
    short* __restrict__ out, const float* __restrict__ x,
    const float* __restrict__ e, const float* __restrict__ c,
    int D, int Dpad, int Kext, int extN, int total)
{
    int i = blockIdx.x * 256 + threadIdx.x;
    if (i >= total) return;
    int b = i / Kext, k = i - b * Kext;
    float v = 0.f;
    if (k < D) v = x[(size_t)b * D + k];
    else if (k >= Dpad) {
        int j = k - Dpad;
        if (e && j < extN)       v = e[(size_t)b * 45 + j];
        else if (c && j == extN) v = c[b];
    }
    out[i] = f2bf(v);
}

__global__ __launch_bounds__(256) void padbf(
    short* __restrict__ out, const float* __restrict__ in,
    int K, int Kpad, int total)
{
    int i = blockIdx.x * 256 + threadIdx.x;
    if (i >= total) return;
    int n = i / Kpad, k = i - n * Kpad;
    out[i] = (k < K) ? f2bf(in[(size_t)n * K + k]) : (short)0;
}

__global__ __launch_bounds__(256) void convtrans(
    short* __restrict__ out, const float* __restrict__ in,
    int K, int N, int Kpad, int total)
{
    int i = blockIdx.x * 256 + threadIdx.x;
    if (i >= total) return;
    int n = i / Kpad, k = i - n * Kpad;
    out[i] = (k < K && n < N) ? f2bf(in[(size_t)k * N + n]) : (short)0;
}

__global__ __launch_bounds__(256) void padx(
    float* __restrict__ out, const float* __restrict__ in,
    int D, int Dpad, int total)
{
    int i = blockIdx.x * 256 + threadIdx.x;
    if (i >= total) return;
    int b = i / Dpad, d = i - b * Dpad;
    out[i] = (d < D) ? in[(size_t)b * D + d] : 0.f;
}

__global__ __launch_bounds__(256) void padvec(
    float* __restrict__ out, const float* __restrict__ in, int N, int Npad)
{
    int i = blockIdx.x * 256 + threadIdx.x;
    if (i < Npad) out[i] = (i < N) ? in[i] : 0.f;
}

// b31[n] = sum_d b3[d]*W1[d][n] ; one block per n
__global__ __launch_bounds__(256) void b31k(
    float* __restrict__ b31, const float* __restrict__ b3,
    const float* __restrict__ W1, int D)
{
    __shared__ float ps[4];
    int n = blockIdx.x;
    int lane = threadIdx.x & 63, wave = threadIdx.x >> 6;
    float s = 0.f;
    for (int d = threadIdx.x; d < D; d += 256)
        s = fmaf(b3[d], W1[(size_t)d * 512 + n], s);
    #pragma unroll
    for (int off = 32; off; off >>= 1) s += __shfl_down(s, off, 64);
    if (lane == 0) ps[wave] = s;
    __syncthreads();
    if (threadIdx.x == 0) b31[n] = ps[0] + ps[1] + ps[2] + ps[3];
}

// vbufp[(bi*512+tid)*32+e] = vb[m0+mt*16+lr*4+r][wave*64+nt*16+lc]
__global__ __launch_bounds__(512) void permvb(
    short* __restrict__ out, const short* __restrict__ in)
{
    int bi = blockIdx.x, tid = threadIdx.x;
    int wave = tid >> 6, lane = tid & 63, lr = lane >> 4, lc = lane & 15;
    int m0 = bi * 32;
    size_t obase = ((size_t)((bi << 9) + tid)) << 5;
    #pragma unroll
    for (int q = 0; q < 4; ++q) {
        bf8 o;
        #pragma unroll
        for (int k = 0; k < 8; ++k) {
            int e = q * 8 + k;
            int nt = e >> 3, mt = (e >> 2) & 1, r = e & 3;
            int row = m0 + mt * 16 + lr * 4 + r;
            int col = (wave << 6) + (nt << 4) + lc;
            o[k] = in[((size_t)row << 9) + col];
        }
        *(bf8*)(out + obase + (q << 3)) = o;
    }
}

__global__ __launch_bounds__(256) void final_reduce(
    const float* __restrict__ z, const float* __restrict__ L,
    float* __restrict__ acc, int Dpad, int Dtrue)
{
    __shared__ float ps[4];
    int wave = threadIdx.x >> 6, lane = threadIdx.x & 63;
    int row = blockIdx.x * 4 + wave;
    const float* zp = z + (size_t)row * Dpad;
    float s = 0.f;
    for (int d = lane; d < Dpad; d += 64) { float x = zp[d]; s = fmaf(x, x, s); }
    #pragma unroll
    for (int off = 32; off; off >>= 1) s += __shfl_down(s, off, 64);
    if (lane == 0) ps[wave] = -0.5f * s - 0.5f * (float)Dtrue * LOG2PI + L[row];
    __syncthreads();
    if (threadIdx.x == 0) atomicAdd(acc, ps[0] + ps[1] + ps[2] + ps[3]);
}

__global__ void finalize_k(float* __restrict__ out, const float* __restrict__ acc)
{
    out[0] = -(acc[0] + acc[1]) * (1.f / 8192.f);
}

// ---------------------------------------------------------------------------
extern "C" void kernel_launch(void* const* d_in, const int* in_sizes, int n_in,
                              void* d_out, int out_size, void* d_ws, size_t ws_size,
                              hipStream_t stream)
{
    (void)in_sizes; (void)n_in; (void)out_size; (void)ws_size;
    const float* voxel  = (const float*)d_in[0];
    const float* energy = (const float*)d_in[1];
    const float* cond   = (const float*)d_in[2];
    const float* eps_v  = (const float*)d_in[3];
    const float* eps_e  = (const float*)d_in[4];
    const float* Wt[2][5] = {
        {(const float*)d_in[5], (const float*)d_in[6], (const float*)d_in[7], (const float*)d_in[8], (const float*)d_in[9]},
        {(const float*)d_in[11],(const float*)d_in[12],(const float*)d_in[13],(const float*)d_in[14],(const float*)d_in[15]}};
    const float* b3t[2] = {(const float*)d_in[10], (const float*)d_in[16]};

    const int Bn = 8192, H = 512;
    const size_t BH = (size_t)Bn * H;

    char* wp = (char*)d_ws;
    auto alloc = [&](size_t bytes) { char* p = wp; wp += (bytes + 255) & ~(size_t)255; return p; };
    FA fa[2];
    for (int f = 0; f < 2; ++f) {
        fa[f].Pcurb = (short*)alloc(BH * 2);
        fa[f].th1b  = (short*)alloc(BH * 2);
        fa[f].vbufp = (short*)alloc(BH * 2);
        fa[f].Pk    = (short*)alloc(5 * BH * 2);
        fa[f].xf    = (float*)alloc((size_t)Bn * (f ? 64 : 512) * 4);
        fa[f].w2t   = (short*)alloc((size_t)512 * 512 * 2);
        fa[f].w3c   = (short*)alloc((size_t)(f ? 576 : 1024) * 512 * 2);
        fa[f].b3p   = (float*)alloc(512 * 4);
        fa[f].b31   = (float*)alloc(512 * 4);
        fa[f].L     = (float*)alloc(Bn * 4);
    }
    short* abx   = (short*)alloc((size_t)Bn * 576 * 2);
    short* abeps = (short*)alloc((size_t)Bn * 576 * 2);
    short* vbtmp = (short*)alloc(BH * 2);
    short* w1x   = (short*)alloc((size_t)512 * 576 * 2);
    short* w3bt  = (short*)alloc((size_t)512 * 576 * 2);
    float* w31f  = (float*)alloc((size_t)512 * 512 * 4);
    float* acc   = (float*)alloc(256);

    (void)hipMemsetAsync(acc, 0, 2 * sizeof(float), stream);

    static const double Bcf[6] = {35.0/384, 0.0, 500.0/1113, 125.0/192, -2187.0/6784, 11.0/84};
    const double dtd = -0.1;

    for (int flow = 0; flow < 2; ++flow) {
        const int D    = (flow == 0) ? 504 : 45;
        const int Dpad = (flow == 0) ? 512 : 64;
        const int Kext = Dpad + 64;
        const int extN = (flow == 0) ? 45 : 0;
        const int rowE = (flow == 0) ? 505 : 0;
        const int rowC = (flow == 0) ? 550 : 46;
        const float* x_in = (flow == 0) ? voxel : energy;
        const float* eps  = (flow == 0) ? eps_v : eps_e;
        const float* ecnd = (flow == 0) ? energy : nullptr;
        const float* W1 = Wt[flow][0]; const float* b1 = Wt[flow][1];
        const float* W2 = Wt[flow][2]; const float* b2 = Wt[flow][3];
        const float* W3 = Wt[flow][4]; const float* b3 = b3t[flow];
        fa[flow].b2  = b2;
        fa[flow].wtp = W1 + (size_t)D * H;

        (void)hipMemsetAsync(fa[flow].L, 0, Bn * sizeof(float), stream);

        buildw1x<<<(512 * Kext + 255) / 256, 256, 0, stream>>>(
            w1x, W1, D, Dpad, Kext, extN, rowE, rowC, 512 * Kext);
        buildab<<<(Bn * Kext + 255) / 256, 256, 0, stream>>>(
            abx, x_in, ecnd, cond, D, Dpad, Kext, extN, Bn * Kext);
        buildab<<<(Bn * Kext + 255) / 256, 256, 0, stream>>>(
            abeps, eps, nullptr, nullptr, D, Dpad, Kext, extN, Bn * Kext);
        padbf<<<(512 * Kext + 255) / 256, 256, 0, stream>>>(w3bt, W3, D, Kext, 512 * Kext);
        convtrans<<<(512 * 512 + 255) / 256, 256, 0, stream>>>(
            (short*)fa[flow].w2t, W2, 512, 512, 512, 512 * 512);
        mgemm0<0><<<dim3(4, 4), 256, 0, stream>>>(w3bt, w1x, Kext, w31f, nullptr, nullptr);
        convtrans<<<(Dpad * 512 + 255) / 256, 256, 0, stream>>>(
            (short*)fa[flow].w3c, W3, 512, D, 512, Dpad * 512);
        convtrans<<<(512 * 512 + 255) / 256, 256, 0, stream>>>(
            (short*)fa[flow].w3c + (size_t)Dpad * 512, w31f, 512, 512, 512, 512 * 512);
        b31k<<<512, 256, 0, stream>>>((float*)fa[flow].b31, b3, W1, D);
        padvec<<<2, 256, 0, stream>>>((float*)fa[flow].b3p, b3, D, Dpad);
        padx<<<(Bn * Dpad + 255) / 256, 256, 0, stream>>>(fa[flow].xf, x_in, D, Dpad, Bn * Dpad);

        mgemm0<1><<<dim3(4, 64), 256, 0, stream>>>(abx, w1x, Kext,
            nullptr, fa[flow].Pcurb, b1);
        mgemm0<1><<<dim3(4, 64), 256, 0, stream>>>(abeps, w1x, Kext,
            nullptr, (short*)fa[flow].th1b, nullptr);
        mgemm0<1><<<dim3(4, 64), 256, 0, stream>>>(abeps, w3bt, Kext,
            nullptr, vbtmp, nullptr);
        permvb<<<256, 512, 0, stream>>>((short*)fa[flow].vbufp, vbtmp);
    }

    const float db0 = (float)(dtd * Bcf[0]), db2 = (float)(dtd * Bcf[2]),
                db3 = (float)(dtd * Bcf[3]), db4 = (float)(dtd * Bcf[4]),
                db5 = (float)(dtd * Bcf[5]);

    for (int s = 0; s < 10; ++s)
        for (int iA = 0; iA < 6; iA += 2)
            pair2_k<<<512, 512, 0, stream>>>(fa[0], fa[1], s, iA,
                db0, db2, db3, db4, db5);

    final_reduce<<<Bn / 4, 256, 0, stream>>>(fa[0].xf, fa[0].L, acc + 0, 512, 504);
    final_reduce<<<Bn / 4, 256, 0, stream>>>(fa[1].xf, fa[1].L, acc + 1, 64, 45);
    finalize_k<<<1, 1, 0, stream>>>((float*)d_out, acc);
}

// Round 19
// 6500.394 us; speedup vs baseline: 2.2413x; 2.2413x over previous
//
#include <hip/hip_runtime.h>
#include <math.h>
#include <stdint.h>

#define LOG2PI 1.8378770664093453f

typedef __attribute__((ext_vector_type(8))) short bf8;   // 8 bf16
typedef __attribute__((ext_vector_type(4))) float f4;

__device__ __forceinline__ short f2bf(float f) {
    uint32_t u = __float_as_uint(f);
    u += 0x7fffu + ((u >> 16) & 1u);          // RNE
    return (short)(u >> 16);
}
__device__ __forceinline__ float bf2f(unsigned short u) {
    return __uint_as_float(((uint32_t)u) << 16);
}
__device__ __forceinline__ float tanh_fast(float x) {
    // tanh(x) = 1 - 2/(1+e^{2x}); v_exp_f32 + v_rcp_f32, branchless, ~1e-6 abs
    float t = __builtin_amdgcn_exp2f(x * 2.88539008177793f);
    return 1.f - 2.f * __builtin_amdgcn_rcpf(1.f + t);
}
// Plain (cacheable) loads — R7's non-temporal hints bypassed cache; removing
// them (R16) gave within-stage L2 hits: 155 -> 137 us/stage.
__device__ __forceinline__ bf8 ntl8(const short* p) {
    return *(const bf8*)p;
}
__device__ __forceinline__ void gload16(const void* g, void* l) {
    __builtin_amdgcn_global_load_lds(
        (const __attribute__((address_space(1))) uint32_t*)(uintptr_t)g,
        (__attribute__((address_space(3))) uint32_t*)(uintptr_t)l, 16, 0, 0);
}

struct FA {                      // per-flow pointer bundle
    float* Pcurf; short* Pcurb; const short* th1b; const short* vbufp;
    short* Pk; float* xf;
    const short* w2t; const short* w3c;
    const float* b2; const float* b3p; const float* b31; const float* wtp;
    float* L;
};

// ---------------------------------------------------------------------------
// Combined per-stage kernel: blocks 0-255 flow0 (32 rows each), 256-511 flow1.
// R16 structure (best measured: 6.51ms). Per-stage dispatch keeps all blocks
// phase-synchronized so the weight streams are shared in L2 (R14/R17/R18:
// every multi-stage-per-dispatch variant desynchronized blocks and ballooned
// traffic). R19 adds s_setprio around MFMA clusters (T5: the 2 co-resident
// blocks/CU are at independent phases -> scheduler has something to arbitrate).
// B: pre1 = Pcurb + sum c_j Pk_j + ti*wt -> a1(LDS rows 0-31)/ta1(rows 32-63)
// C: [a1;ta1] @ W2 -> acc[4][4]; epi: a2=tanh overlays rows 0-31; trace->L
// D-A: xf += tcoef*(a2 @ W3 + b3)
// D-B: P = a2 @ W31 + b31 staged to LDS rows 32-63 (ta1 dead after C), then
//      one flat coalesced pass (16B/lane) for Pk store / Pcur RMW.
// ---------------------------------------------------------------------------
__global__ __launch_bounds__(512, 2) void stage2_k(
    FA f0, FA f1, int i, float ti,
    float c0, float c1, float c2, float c3, float c4,
    float tcoef, float db0, float db2, float db3, float db4, float db5)
{
    __shared__ char lds[65536];   // [64 rows][512 bf16]; a2 overlays rows 0-31
    const int tid = threadIdx.x, wave = tid >> 6, lane = tid & 63;
    const int lr = lane >> 4, lc = lane & 15;
    const int fl = blockIdx.x >> 8;
    const int bi = blockIdx.x & 255;
    const int m0 = bi * 32;
    const FA F = fl ? f1 : f0;
    const int dpad = fl ? 64 : 512;
    const bool doTan = (i != 1);
    const size_t BH = (size_t)8192 * 512;
    const float cj[5] = {c0, c1, c2, c3, c4};

    // ---------------- Phase B (coalesced, bf8 granularity) ----------------
    #pragma unroll
    for (int g = 0; g < 4; ++g) {
        int flat = (g << 12) + (tid << 3);    // 0..16383, 8-elem chunks
        int row = flat >> 9;                   // 0..31
        int cc  = flat & 511;                  // col, multiple of 8
        size_t gb = (((size_t)(m0 + row)) << 9) + cc;
        bf8 pcb = ntl8(F.Pcurb + gb);
        float4 w0 = *(const float4*)(F.wtp + cc);
        float4 w1 = *(const float4*)(F.wtp + cc + 4);
        float wv[8] = {w0.x,w0.y,w0.z,w0.w,w1.x,w1.y,w1.z,w1.w};
        float pre[8];
        #pragma unroll
        for (int e = 0; e < 8; ++e)
            pre[e] = fmaf(ti, wv[e], bf2f((unsigned short)pcb[e]));
        #pragma unroll
        for (int j = 0; j < 5; ++j) {
            if (j < i) {
                bf8 v = ntl8(F.Pk + (size_t)j * BH + gb);
                #pragma unroll
                for (int e = 0; e < 8; ++e)
                    pre[e] = fmaf(cj[j], bf2f((unsigned short)v[e]), pre[e]);
            }
        }
        int wb = (row << 10) + ((cc << 1) ^ ((row & 7) << 4));
        bf8 o1, o2;
        if (doTan) {
            bf8 th = ntl8(F.th1b + gb);
            #pragma unroll
            for (int e = 0; e < 8; ++e) {
                float a = tanh_fast(pre[e]);
                o1[e] = f2bf(a);
                o2[e] = f2bf((1.f - a * a) * bf2f((unsigned short)th[e]));
            }
            *(bf8*)(lds + wb) = o1;
            *(bf8*)(lds + 32768 + wb) = o2;   // (32+row)&7 == row&7
        } else {
            #pragma unroll
            for (int e = 0; e < 8; ++e) o1[e] = f2bf(tanh_fast(pre[e]));
            *(bf8*)(lds + wb) = o1;
        }
    }
    __syncthreads();

    // ---------------- Phase C: [a1;ta1](64) @ W2 ----------------
    f4 acc[4][4];
    #pragma unroll
    for (int mt = 0; mt < 4; ++mt)
        #pragma unroll
        for (int nt = 0; nt < 4; ++nt) acc[mt][nt] = (f4)0.0f;
    {
        const short* wb = F.w2t + ((size_t)((wave << 6) + lc) << 9) + (lr << 3);
        bf8 bc[4], bn[4];
        #pragma unroll
        for (int nt = 0; nt < 4; ++nt) bc[nt] = *(const bf8*)(wb + (nt << 13));
        __builtin_amdgcn_s_setprio(1);
        for (int kt = 0; kt < 16; ++kt) {
            bf8 af[4];
            int kb = (kt << 6) + (lr << 4);
            #pragma unroll
            for (int mt = 0; mt < 4; ++mt) {
                if (mt >= 2 && !doTan) continue;
                int lrow = (mt << 4) + lc;
                af[mt] = *(const bf8*)(lds + (lrow << 10) + (kb ^ ((lrow & 7) << 4)));
            }
            if (kt < 15) {
                #pragma unroll
                for (int nt = 0; nt < 4; ++nt)
                    bn[nt] = *(const bf8*)(wb + (nt << 13) + ((kt + 1) << 5));
            }
            #pragma unroll
            for (int mt = 0; mt < 4; ++mt) {
                if (mt >= 2 && !doTan) continue;
                #pragma unroll
                for (int nt = 0; nt < 4; ++nt)
                    acc[mt][nt] = __builtin_amdgcn_mfma_f32_16x16x32_bf16(
                        af[mt], bc[nt], acc[mt][nt], 0, 0, 0);
            }
            #pragma unroll
            for (int nt = 0; nt < 4; ++nt) bc[nt] = bn[nt];
        }
        __builtin_amdgcn_s_setprio(0);
    }
    __syncthreads();   // all a1/ta1 reads done before a2 overlay

    // ---------------- Phase C epilogue: a2 -> rows 0-31; trace -> L -------
    {
        bf8 vb[4];
        if (doTan) {
            size_t vbase = ((size_t)((bi << 9) + tid)) << 5;
            #pragma unroll
            for (int q = 0; q < 4; ++q) vb[q] = ntl8(F.vbufp + vbase + (q << 3));
        }
        float trp[2][4] = {{0.f,0.f,0.f,0.f},{0.f,0.f,0.f,0.f}};
        #pragma unroll
        for (int mt = 0; mt < 2; ++mt)
            #pragma unroll
            for (int nt = 0; nt < 4; ++nt) {
                int col = (wave << 6) + (nt << 4) + lc;
                float bb = F.b2[col];
                #pragma unroll
                for (int r = 0; r < 4; ++r) {
                    int lrow = (mt << 4) + (lr << 2) + r;
                    float a = tanh_fast(acc[mt][nt][r] + bb);
                    *(short*)(lds + (lrow << 10) + ((col << 1) ^ ((lrow & 7) << 4))) = f2bf(a);
                    if (doTan) {
                        int e = nt * 8 + mt * 4 + r;
                        float ta2 = (1.f - a * a) * acc[mt + 2][nt][r];
                        trp[mt][r] = fmaf(ta2,
                            bf2f((unsigned short)vb[e >> 3][e & 7]), trp[mt][r]);
                    }
                }
            }
        if (doTan) {
            #pragma unroll
            for (int mt = 0; mt < 2; ++mt)
                #pragma unroll
                for (int r = 0; r < 4; ++r) {
                    float v = trp[mt][r];
                    v += __shfl_xor(v, 1); v += __shfl_xor(v, 2);
                    v += __shfl_xor(v, 4); v += __shfl_xor(v, 8);
                    if (lc == 0)
                        atomicAdd(&F.L[m0 + (mt << 4) + (lr << 2) + r], tcoef * v);
                }
        }
    }
    __syncthreads();   // a2 visible

    // ---------------- Phase D chunk A: xf += tcoef*(a2 @ W3 + b3) ---------
    if (doTan) {
        if (fl == 0) {
            f4 aA[2][4];
            #pragma unroll
            for (int mt = 0; mt < 2; ++mt)
                #pragma unroll
                for (int nt = 0; nt < 4; ++nt) aA[mt][nt] = (f4)0.0f;
            const short* wA = F.w3c + ((size_t)((wave << 6) + lc) << 9) + (lr << 3);
            bf8 bc[4], bn[4];
            #pragma unroll
            for (int nt = 0; nt < 4; ++nt) bc[nt] = *(const bf8*)(wA + (nt << 13));
            __builtin_amdgcn_s_setprio(1);
            for (int kt = 0; kt < 16; ++kt) {
                bf8 af[2];
                int kb = (kt << 6) + (lr << 4);
                #pragma unroll
                for (int mt = 0; mt < 2; ++mt) {
                    int lrow = (mt << 4) + lc;
                    af[mt] = *(const bf8*)(lds + (lrow << 10) + (kb ^ ((lrow & 7) << 4)));
                }
                if (kt < 15) {
                    #pragma unroll
                    for (int nt = 0; nt < 4; ++nt)
                        bn[nt] = *(const bf8*)(wA + (nt << 13) + ((kt + 1) << 5));
                }
                #pragma unroll
                for (int mt = 0; mt < 2; ++mt)
                    #pragma unroll
                    for (int nt = 0; nt < 4; ++nt)
                        aA[mt][nt] = __builtin_amdgcn_mfma_f32_16x16x32_bf16(
                            af[mt], bc[nt], aA[mt][nt], 0, 0, 0);
                #pragma unroll
                for (int nt = 0; nt < 4; ++nt) bc[nt] = bn[nt];
            }
            __builtin_amdgcn_s_setprio(0);
            #pragma unroll
            for (int mt = 0; mt < 2; ++mt)
                #pragma unroll
                for (int nt = 0; nt < 4; ++nt) {
                    int col = (wave << 6) + (nt << 4) + lc;
                    float bb = F.b3p[col];
                    #pragma unroll
                    for (int r = 0; r < 4; ++r) {
                        size_t grow = (size_t)(m0 + (mt << 4) + (lr << 2) + r);
                        size_t xi = (grow << 9) + col;
                        F.xf[xi] = fmaf(tcoef, aA[mt][nt][r] + bb, F.xf[xi]);
                    }
                }
        } else if (wave < 4) {
            f4 aA[2];
            aA[0] = (f4)0.0f; aA[1] = (f4)0.0f;
            int col = (wave << 4) + lc;
            const short* wA = F.w3c + ((size_t)col << 9) + (lr << 3);
            bf8 bc = *(const bf8*)wA, bn;
            for (int kt = 0; kt < 16; ++kt) {
                bf8 af[2];
                int kb = (kt << 6) + (lr << 4);
                #pragma unroll
                for (int mt = 0; mt < 2; ++mt) {
                    int lrow = (mt << 4) + lc;
                    af[mt] = *(const bf8*)(lds + (lrow << 10) + (kb ^ ((lrow & 7) << 4)));
                }
                if (kt < 15) bn = *(const bf8*)(wA + ((kt + 1) << 5));
                #pragma unroll
                for (int mt = 0; mt < 2; ++mt)
                    aA[mt] = __builtin_amdgcn_mfma_f32_16x16x32_bf16(
                        af[mt], bc, aA[mt], 0, 0, 0);
                bc = bn;
            }
            float bb = F.b3p[col];
            #pragma unroll
            for (int mt = 0; mt < 2; ++mt)
                #pragma unroll
                for (int r = 0; r < 4; ++r) {
                    size_t grow = (size_t)(m0 + (mt << 4) + (lr << 2) + r);
                    size_t xi = (grow << 6) + col;
                    F.xf[xi] = fmaf(tcoef, aA[mt][r] + bb, F.xf[xi]);
                }
        }
    }

    // ---------------- Phase D chunk B: P = a2 @ W31 + b31 -----------------
    {
        f4 aB[2][4];
        #pragma unroll
        for (int mt = 0; mt < 2; ++mt)
            #pragma unroll
            for (int nt = 0; nt < 4; ++nt) aB[mt][nt] = (f4)0.0f;
        const short* wB = F.w3c + ((size_t)(dpad + (wave << 6) + lc) << 9) + (lr << 3);
        bf8 bc[4], bn[4];
        #pragma unroll
        for (int nt = 0; nt < 4; ++nt) bc[nt] = *(const bf8*)(wB + (nt << 13));
        __builtin_amdgcn_s_setprio(1);
        for (int kt = 0; kt < 16; ++kt) {
            bf8 af[2];
            int kb = (kt << 6) + (lr << 4);
            #pragma unroll
            for (int mt = 0; mt < 2; ++mt) {
                int lrow = (mt << 4) + lc;
                af[mt] = *(const bf8*)(lds + (lrow << 10) + (kb ^ ((lrow & 7) << 4)));
            }
            if (kt < 15) {
                #pragma unroll
                for (int nt = 0; nt < 4; ++nt)
                    bn[nt] = *(const bf8*)(wB + (nt << 13) + ((kt + 1) << 5));
            }
            #pragma unroll
            for (int mt = 0; mt < 2; ++mt)
                #pragma unroll
                for (int nt = 0; nt < 4; ++nt)
                    aB[mt][nt] = __builtin_amdgcn_mfma_f32_16x16x32_bf16(
                        af[mt], bc[nt], aB[mt][nt], 0, 0, 0);
            #pragma unroll
            for (int nt = 0; nt < 4; ++nt) bc[nt] = bn[nt];
        }
        __builtin_amdgcn_s_setprio(0);
        // stage P fragments to LDS rows 32-63 (ta1 region, dead after C)
        #pragma unroll
        for (int mt = 0; mt < 2; ++mt)
            #pragma unroll
            for (int nt = 0; nt < 4; ++nt) {
                int colh = (wave << 6) + (nt << 4) + lc;
                float bb = F.b31[colh];
                #pragma unroll
                for (int r = 0; r < 4; ++r) {
                    int lrow = (mt << 4) + (lr << 2) + r;   // 0..31
                    *(short*)(lds + 32768 + (lrow << 10) +
                        ((colh << 1) ^ ((lrow & 7) << 4))) = f2bf(aB[mt][nt][r] + bb);
                }
            }
    }
    __syncthreads();   // staged P visible

    // ---------------- flat coalesced P write / Pcur update ----------------
    #pragma unroll
    for (int g = 0; g < 4; ++g) {
        int flat = (g << 12) + (tid << 3);
        int row = flat >> 9;
        int cc  = flat & 511;
        size_t gb = (((size_t)(m0 + row)) << 9) + cc;
        bf8 pv = *(const bf8*)(lds + 32768 + (row << 10) +
                               ((cc << 1) ^ ((row & 7) << 4)));
        if (i < 5) {
            *(bf8*)(F.Pk + (size_t)i * BH + gb) = pv;
        } else {
            bf8 v0 = ntl8(F.Pk + 0 * BH + gb);
            bf8 v2 = ntl8(F.Pk + 2 * BH + gb);
            bf8 v3 = ntl8(F.Pk + 3 * BH + gb);
            bf8 v4 = ntl8(F.Pk + 4 * BH + gb);
            float4 pf0 = *(const float4*)(F.Pcurf + gb);
            float4 pf1 = *(const float4*)(F.Pcurf + gb + 4);
            float pf[8] = {pf0.x,pf0.y,pf0.z,pf0.w,pf1.x,pf1.y,pf1.z,pf1.w};
            bf8 ob;
            #pragma unroll
            for (int e = 0; e < 8; ++e) {
                float pn = pf[e];
                pn = fmaf(db0, bf2f((unsigned short)v0[e]), pn);
                pn = fmaf(db2, bf2f((unsigned short)v2[e]), pn);
                pn = fmaf(db3, bf2f((unsigned short)v3[e]), pn);
                pn = fmaf(db4, bf2f((unsigned short)v4[e]), pn);
                pn = fmaf(db5, bf2f((unsigned short)pv[e]), pn);
                pf[e] = pn;
                ob[e] = f2bf(pn);
            }
            *(float4*)(F.Pcurf + gb)     = make_float4(pf[0], pf[1], pf[2], pf[3]);
            *(float4*)(F.Pcurf + gb + 4) = make_float4(pf[4], pf[5], pf[6], pf[7]);
            *(bf8*)(F.Pcurb + gb) = ob;
        }
    }
}

// ---------------------------------------------------------------------------
// bf16 MFMA GEMM (precomputes): out(M x 512) = A(M x K) @ Bt(512 x K)^T + bias
// OUT 0: f32; OUT 1: bf16; OUT 2: both. grid (4, M/128).
// ---------------------------------------------------------------------------
template<int OUT>
__global__ __launch_bounds__(256) void mgemm0(
    const short* __restrict__ A, const short* __restrict__ Bt, int K,
    float* __restrict__ Cf, short* __restrict__ Cb,
    const float* __restrict__ bias)
{
    __shared__ char lds[32768];
    const int tid = threadIdx.x, wave = tid >> 6, lane = tid & 63;
    const int m0 = blockIdx.y * 128, n0 = blockIdx.x * 128;
    const int wr = wave >> 1, wc = wave & 1;

    f4 acc[4][4];
    #pragma unroll
    for (int m = 0; m < 4; ++m)
        #pragma unroll
        for (int n = 0; n < 4; ++n) acc[m][n] = (f4)0.0f;

    const int cbs  = (((lane & 7) ^ (lane >> 3)) << 4);
    const int lrow = lane >> 3;

    for (int k0 = 0; k0 < K; k0 += 64) {
        __syncthreads();
        #pragma unroll
        for (int i = 0; i < 4; ++i) {
            int q = wave * 4 + i;
            int row = q * 8 + lrow;
            gload16((const char*)(A  + (size_t)(m0 + row) * K + k0) + cbs, lds + q * 1024);
            gload16((const char*)(Bt + (size_t)(n0 + row) * K + k0) + cbs, lds + 16384 + q * 1024);
        }
        __syncthreads();
        #pragma unroll
        for (int kk = 0; kk < 2; ++kk) {
            bf8 af[4], bfr[4];
            #pragma unroll
            for (int m = 0; m < 4; ++m) {
                int row = wr * 64 + m * 16 + (lane & 15);
                int cb  = (((lane >> 4) << 4) + (kk << 6)) ^ ((row & 7) << 4);
                af[m] = *(const bf8*)(lds + row * 128 + cb);
            }
            #pragma unroll
            for (int n = 0; n < 4; ++n) {
                int row = wc * 64 + n * 16 + (lane & 15);
                int cb  = (((lane >> 4) << 4) + (kk << 6)) ^ ((row & 7) << 4);
                bfr[n] = *(const bf8*)(lds + 16384 + row * 128 + cb);
            }
            #pragma unroll
            for (int m = 0; m < 4; ++m)
                #pragma unroll
                for (int n = 0; n < 4; ++n)
                    acc[m][n] = __builtin_amdgcn_mfma_f32_16x16x32_bf16(
                        af[m], bfr[n], acc[m][n], 0, 0, 0);
        }
    }

    #pragma unroll
    for (int m = 0; m < 4; ++m)
        #pragma unroll
        for (int r = 0; r < 4; ++r) {
            int grow = m0 + wr * 64 + m * 16 + (lane >> 4) * 4 + r;
            #pragma unroll
            for (int n = 0; n < 4; ++n) {
                int gcol = n0 + wc * 64 + n * 16 + (lane & 15);
                float v = acc[m][n][r];
                if (bias) v += bias[gcol];
                if constexpr (OUT == 0) Cf[(size_t)grow * 512 + gcol] = v;
                else if constexpr (OUT == 1) Cb[(size_t)grow * 512 + gcol] = f2bf(v);
                else {
                    Cf[(size_t)grow * 512 + gcol] = v;
                    Cb[(size_t)grow * 512 + gcol] = f2bf(v);
                }
            }
        }
}

// ---------------------------------------------------------------------------
// prep kernels
// ---------------------------------------------------------------------------
__global__ __launch_bounds__(256) void buildw1x(
    short* __restrict__ out, const float* __restrict__ W1,
    int D, int Dpad, int Kext, int extN, int rowE, int rowC, int total)
{
    int i = blockIdx.x * 256 + threadIdx.x;
    if (i >= total) return;
    int n = i / Kext, k = i - n * Kext;
    float v = 0.f;
    if (k < D) v = W1[(size_t)k * 512 + n];
    else if (k >= Dpad) {
        int j = k - Dpad;
        if (j < extN)       v = W1[(size_t)(rowE + j) * 512 + n];
        else if (j == extN) v = W1[(size_t)rowC * 512 + n];
    }
    out[i] = f2bf(v);
}

__global__ __launch_bounds__(256) void buildab(
    short* __restrict__ out, const float* __restrict__ x,
    const float* __restrict__ e, const float* __restrict__ c,
    int D, int Dpad, int Kext, int extN, int total)
{
    int i = blockIdx.x * 256 + threadIdx.x;
    if (i >= total) return;
    int b = i / Kext, k = i - b * Kext;
    float v = 0.f;
    if (k < D) v = x[(size_t)b * D + k];
    else if (k >= Dpad) {
        int j = k - Dpad;
        if (e && j < extN)       v = e[(size_t)b * 45 + j];
        else if (c && j == extN) v = c[b];
    }
    out[i] = f2bf(v);
}

__global__ __launch_bounds__(256) void padbf(
    short* __restrict__ out, const float* __restrict__ in,
    int K, int Kpad, int total)
{
    int i = blockIdx.x * 256 + threadIdx.x;
    if (i >= total) return;
    int n = i / Kpad, k = i - n * Kpad;
    out[i] = (k < K) ? f2bf(in[(size_t)n * K + k]) : (short)0;
}

__global__ __launch_bounds__(256) void convtrans(
    short* __restrict__ out, const float* __restrict__ in,
    int K, int N, int Kpad, int total)
{
    int i = blockIdx.x * 256 + threadIdx.x;
    if (i >= total) return;
    int n = i / Kpad, k = i - n * Kpad;
    out[i] = (k < K && n < N) ? f2bf(in[(size_t)k * N + n]) : (short)0;
}

__global__ __launch_bounds__(256) void padx(
    float* __restrict__ out, const float* __restrict__ in,
    int D, int Dpad, int total)
{
    int i = blockIdx.x * 256 + threadIdx.x;
    if (i >= total) return;
    int b = i / Dpad, d = i - b * Dpad;
    out[i] = (d < D) ? in[(size_t)b * D + d] : 0.f;
}

__global__ __launch_bounds__(256) void padvec(
    float* __restrict__ out, const float* __restrict__ in, int N, int Npad)
{
    int i = blockIdx.x * 256 + threadIdx.x;
    if (i < Npad) out[i] = (i < N) ? in[i] : 0.f;
}

// b31[n] = sum_d b3[d]*W1[d][n] ; one block per n
__global__ __launch_bounds__(256) void b31k(
    float* __restrict__ b31, const float* __restrict__ b3,
    const float* __restrict__ W1, int D)
{
    __shared__ float ps[4];
    int n = blockIdx.x;
    int lane = threadIdx.x & 63, wave = threadIdx.x >> 6;
    float s = 0.f;
    for (int d = threadIdx.x; d < D; d += 256)
        s = fmaf(b3[d], W1[(size_t)d * 512 + n], s);
    #pragma unroll
    for (int off = 32; off; off >>= 1) s += __shfl_down(s, off, 64);
    if (lane == 0) ps[wave] = s;
    __syncthreads();
    if (threadIdx.x == 0) b31[n] = ps[0] + ps[1] + ps[2] + ps[3];
}

// vbufp[(bi*512+tid)*32+e] = vb[m0+mt*16+lr*4+r][wave*64+nt*16+lc]
__global__ __launch_bounds__(512) void permvb(
    short* __restrict__ out, const short* __restrict__ in)
{
    int bi = blockIdx.x, tid = threadIdx.x;
    int wave = tid >> 6, lane = tid & 63, lr = lane >> 4, lc = lane & 15;
    int m0 = bi * 32;
    size_t obase = ((size_t)((bi << 9) + tid)) << 5;
    #pragma unroll
    for (int q = 0; q < 4; ++q) {
        bf8 o;
        #pragma unroll
        for (int k = 0; k < 8; ++k) {
            int e = q * 8 + k;
            int nt = e >> 3, mt = (e >> 2) & 1, r = e & 3;
            int row = m0 + mt * 16 + lr * 4 + r;
            int col = (wave << 6) + (nt << 4) + lc;
            o[k] = in[((size_t)row << 9) + col];
        }
        *(bf8*)(out + obase + (q << 3)) = o;
    }
}

__global__ __launch_bounds__(256) void final_reduce(
    const float* __restrict__ z, const float* __restrict__ L,
    float* __restrict__ acc, int Dpad, int Dtrue)
{
    __shared__ float ps[4];
    int wave = threadIdx.x >> 6, lane = threadIdx.x & 63;
    int row = blockIdx.x * 4 + wave;
    const float* zp = z + (size_t)row * Dpad;
    float s = 0.f;
    for (int d = lane; d < Dpad; d += 64) { float x = zp[d]; s = fmaf(x, x, s); }
    #pragma unroll
    for (int off = 32; off; off >>= 1) s += __shfl_down(s, off, 64);
    if (lane == 0) ps[wave] = -0.5f * s - 0.5f * (float)Dtrue * LOG2PI + L[row];
    __syncthreads();
    if (threadIdx.x == 0) atomicAdd(acc, ps[0] + ps[1] + ps[2] + ps[3]);
}

__global__ void finalize_k(float* __restrict__ out, const float* __restrict__ acc)
{
    out[0] = -(acc[0] + acc[1]) * (1.f / 8192.f);
}

// ---------------------------------------------------------------------------
extern "C" void kernel_launch(void* const* d_in, const int* in_sizes, int n_in,
                              void* d_out, int out_size, void* d_ws, size_t ws_size,
                              hipStream_t stream)
{
    (void)in_sizes; (void)n_in; (void)out_size; (void)ws_size;
    const float* voxel  = (const float*)d_in[0];
    const float* energy = (const float*)d_in[1];
    const float* cond   = (const float*)d_in[2];
    const float* eps_v  = (const float*)d_in[3];
    const float* eps_e  = (const float*)d_in[4];
    const float* Wt[2][5] = {
        {(const float*)d_in[5], (const float*)d_in[6], (const float*)d_in[7], (const float*)d_in[8], (const float*)d_in[9]},
        {(const float*)d_in[11],(const float*)d_in[12],(const float*)d_in[13],(const float*)d_in[14],(const float*)d_in[15]}};
    const float* b3t[2] = {(const float*)d_in[10], (const float*)d_in[16]};

    const int Bn = 8192, H = 512;
    const size_t BH = (size_t)Bn * H;

    char* wp = (char*)d_ws;
    auto alloc = [&](size_t bytes) { char* p = wp; wp += (bytes + 255) & ~(size_t)255; return p; };
    FA fa[2];
    for (int f = 0; f < 2; ++f) {
        fa[f].Pcurf = (float*)alloc(BH * 4);
        fa[f].Pcurb = (short*)alloc(BH * 2);
        fa[f].th1b  = (short*)alloc(BH * 2);
        fa[f].vbufp = (short*)alloc(BH * 2);
        fa[f].Pk    = (short*)alloc(5 * BH * 2);
        fa[f].xf    = (float*)alloc((size_t)Bn * (f ? 64 : 512) * 4);
        fa[f].w2t   = (short*)alloc((size_t)512 * 512 * 2);
        fa[f].w3c   = (short*)alloc((size_t)(f ? 576 : 1024) * 512 * 2);
        fa[f].b3p   = (float*)alloc(512 * 4);
        fa[f].b31   = (float*)alloc(512 * 4);
        fa[f].L     = (float*)alloc(Bn * 4);
    }
    short* abx   = (short*)alloc((size_t)Bn * 576 * 2);
    short* abeps = (short*)alloc((size_t)Bn * 576 * 2);
    short* vbtmp = (short*)alloc(BH * 2);
    short* w1x   = (short*)alloc((size_t)512 * 576 * 2);
    short* w3bt  = (short*)alloc((size_t)512 * 576 * 2);
    float* w31f  = (float*)alloc((size_t)512 * 512 * 4);
    float* acc   = (float*)alloc(256);

    (void)hipMemsetAsync(acc, 0, 2 * sizeof(float), stream);

    static const double AD[6][5] = {
        {0,0,0,0,0},
        {1.0/5,0,0,0,0},
        {3.0/40,9.0/40,0,0,0},
        {44.0/45,-56.0/15,32.0/9,0,0},
        {19372.0/6561,-25360.0/2187,64448.0/6561,-212.0/729,0},
        {9017.0/3168,-355.0/33,46732.0/5247,49.0/176,-5103.0/18656}};
    static const double Bcf[6] = {35.0/384, 0.0, 500.0/1113, 125.0/192, -2187.0/6784, 11.0/84};
    static const double CD[6]  = {0.0, 0.2, 0.3, 0.8, 8.0/9.0, 1.0};
    const double dtd = -0.1;

    for (int flow = 0; flow < 2; ++flow) {
        const int D    = (flow == 0) ? 504 : 45;
        const int Dpad = (flow == 0) ? 512 : 64;
        const int Kext = Dpad + 64;
        const int extN = (flow == 0) ? 45 : 0;
        const int rowE = (flow == 0) ? 505 : 0;
        const int rowC = (flow == 0) ? 550 : 46;
        const float* x_in = (flow == 0) ? voxel : energy;
        const float* eps  = (flow == 0) ? eps_v : eps_e;
        const float* ecnd = (flow == 0) ? energy : nullptr;
        const float* W1 = Wt[flow][0]; const float* b1 = Wt[flow][1];
        const float* W2 = Wt[flow][2]; const float* b2 = Wt[flow][3];
        const float* W3 = Wt[flow][4]; const float* b3 = b3t[flow];
        fa[flow].b2  = b2;
        fa[flow].wtp = W1 + (size_t)D * H;

        (void)hipMemsetAsync(fa[flow].L, 0, Bn * sizeof(float), stream);

        buildw1x<<<(512 * Kext + 255) / 256, 256, 0, stream>>>(
            w1x, W1, D, Dpad, Kext, extN, rowE, rowC, 512 * Kext);
        buildab<<<(Bn * Kext + 255) / 256, 256, 0, stream>>>(
            abx, x_in, ecnd, cond, D, Dpad, Kext, extN, Bn * Kext);
        buildab<<<(Bn * Kext + 255) / 256, 256, 0, stream>>>(
            abeps, eps, nullptr, nullptr, D, Dpad, Kext, extN, Bn * Kext);
        padbf<<<(512 * Kext + 255) / 256, 256, 0, stream>>>(w3bt, W3, D, Kext, 512 * Kext);
        convtrans<<<(512 * 512 + 255) / 256, 256, 0, stream>>>(
            (short*)fa[flow].w2t, W2, 512, 512, 512, 512 * 512);
        mgemm0<0><<<dim3(4, 4), 256, 0, stream>>>(w3bt, w1x, Kext, w31f, nullptr, nullptr);
        convtrans<<<(Dpad * 512 + 255) / 256, 256, 0, stream>>>(
            (short*)fa[flow].w3c, W3, 512, D, 512, Dpad * 512);
        convtrans<<<(512 * 512 + 255) / 256, 256, 0, stream>>>(
            (short*)fa[flow].w3c + (size_t)Dpad * 512, w31f, 512, 512, 512, 512 * 512);
        b31k<<<512, 256, 0, stream>>>((float*)fa[flow].b31, b3, W1, D);
        padvec<<<2, 256, 0, stream>>>((float*)fa[flow].b3p, b3, D, Dpad);
        padx<<<(Bn * Dpad + 255) / 256, 256, 0, stream>>>(fa[flow].xf, x_in, D, Dpad, Bn * Dpad);

        mgemm0<2><<<dim3(4, 64), 256, 0, stream>>>(abx, w1x, Kext,
            fa[flow].Pcurf, fa[flow].Pcurb, b1);
        mgemm0<1><<<dim3(4, 64), 256, 0, stream>>>(abeps, w1x, Kext,
            nullptr, (short*)fa[flow].th1b, nullptr);
        mgemm0<1><<<dim3(4, 64), 256, 0, stream>>>(abeps, w3bt, Kext,
            nullptr, vbtmp, nullptr);
        permvb<<<256, 512, 0, stream>>>((short*)fa[flow].vbufp, vbtmp);
    }

    const float db0 = (float)(dtd * Bcf[0]), db2 = (float)(dtd * Bcf[2]),
                db3 = (float)(dtd * Bcf[3]), db4 = (float)(dtd * Bcf[4]),
                db5 = (float)(dtd * Bcf[5]);

    for (int s = 0; s < 10; ++s) {
        float t0f = 1.0f + (float)s * -0.1f;
        for (int i = 0; i < 6; ++i) {
            float ti = t0f + (float)(CD[i] * dtd);
            float c[5] = {0,0,0,0,0};
            for (int j = 0; j < i; ++j) c[j] = (float)(dtd * AD[i][j]);
            float tc = (float)(dtd * Bcf[i]);   // 0 for i==1
            stage2_k<<<512, 512, 0, stream>>>(fa[0], fa[1], i, ti,
                c[0], c[1], c[2], c[3], c[4], tc, db0, db2, db3, db4, db5);
        }
    }

    final_reduce<<<Bn / 4, 256, 0, stream>>>(fa[0].xf, fa[0].L, acc + 0, 512, 504);
    final_reduce<<<Bn / 4, 256, 0, stream>>>(fa[1].xf, fa[1].L, acc + 1, 64, 45);
    finalize_k<<<1, 1, 0, stream>>>((float*)d_out, acc);
}